// Round 11
// baseline (370.538 us; speedup 1.0000x reference)
//
#include <hip/hip_runtime.h>
#include <hip/hip_cooperative_groups.h>

namespace cg = cooperative_groups;

#define N_NODES 50000
#define N_EDGES 800000
#define IN_FEATS 256
#define HIDDEN 128
#define OUT_FEATS 64

// ---- LDS-histogram decomposition (packed u16 counters) ----
#define NB 16384             // bins per range (2 bins/u32 word -> 32 KB LDS)
#define NRANGE 4             // ceil(50000/16384)
#define NBT (NRANGE * NB)    // 65536 padded bins per copy (u16 each)
#define NCHUNK 64            // edge chunks (= privatized copies)
#define EPC 12500            // edges per chunk; per-bin count <= 12500 < 2^16

typedef _Float16 f16;
typedef _Float16 f16x8 __attribute__((ext_vector_type(8)));
typedef float f32x4 __attribute__((ext_vector_type(4)));

// --------------------------------------------------- fused preprocessing
// ONE cooperative kernel replacing hist/reduce/scan2/scan3/fill/wtrans
// (R10 accounting: ~10 us launch overhead per dispatch dominated the
// profile — 12 dispatches for ~100 us of kernel work). 256 blocks x 64 KB
// LDS = 2 blocks/CU -> all co-resident (512 cap), cg grid sync between
// phases. Zero global atomics throughout (R3/R4: gfx950 global atomics
// cost ~32 B beyond-L2 traffic each).
__global__ __launch_bounds__(256) void prep_kernel(
    const int* __restrict__ src, const int* __restrict__ dst,
    const float* __restrict__ W1, const float* __restrict__ W2,
    unsigned* __restrict__ hist_src, unsigned* __restrict__ hist_dst,
    int* __restrict__ deg_in, float* __restrict__ norm_src,
    float* __restrict__ norm_dst, int* __restrict__ partial,
    int* __restrict__ rowptr, int* __restrict__ col,
    f16* __restrict__ W1T, f16* __restrict__ W2T) {
  cg::grid_group grid = cg::this_grid();
  __shared__ int lds[NB];  // 64 KB, aliased per phase
  const int bid = blockIdx.x;
  const int tid = threadIdx.x;

  // ---------------- Phase A: LDS histogram (u16 packed, 2 bins/word)
  {
    unsigned* ls = (unsigned*)lds;            // 32 KB
    unsigned* ld2 = (unsigned*)lds + NB / 2;  // 32 KB
    const int r = bid % NRANGE;
    const int c = bid / NRANGE;
    const int lo = r * NB;
    for (int i = tid; i < NB / 2; i += 256) {
      ls[i] = 0;
      ld2[i] = 0;
    }
    __syncthreads();
    const int4* s4 = (const int4*)(src + c * EPC);
    const int4* d4 = (const int4*)(dst + c * EPC);
    for (int i = tid; i < EPC / 4; i += 256) {
      int4 s = s4[i];
      int4 d = d4[i];
      unsigned b;
      b = (unsigned)(s.x - lo); if (b < NB) atomicAdd(&ls[b >> 1], 1u << ((b & 1) << 4));
      b = (unsigned)(s.y - lo); if (b < NB) atomicAdd(&ls[b >> 1], 1u << ((b & 1) << 4));
      b = (unsigned)(s.z - lo); if (b < NB) atomicAdd(&ls[b >> 1], 1u << ((b & 1) << 4));
      b = (unsigned)(s.w - lo); if (b < NB) atomicAdd(&ls[b >> 1], 1u << ((b & 1) << 4));
      b = (unsigned)(d.x - lo); if (b < NB) atomicAdd(&ld2[b >> 1], 1u << ((b & 1) << 4));
      b = (unsigned)(d.y - lo); if (b < NB) atomicAdd(&ld2[b >> 1], 1u << ((b & 1) << 4));
      b = (unsigned)(d.z - lo); if (b < NB) atomicAdd(&ld2[b >> 1], 1u << ((b & 1) << 4));
      b = (unsigned)(d.w - lo); if (b < NB) atomicAdd(&ld2[b >> 1], 1u << ((b & 1) << 4));
    }
    __syncthreads();
    unsigned* hs = hist_src + ((long)c * NBT + lo) / 2;
    unsigned* hd = hist_dst + ((long)c * NBT + lo) / 2;
    for (int i = tid; i < NB / 2; i += 256) {
      hs[i] = ls[i];
      hd[i] = ld2[i];
    }
  }
  grid.sync();

  // ---------------- Phase B: reduce (196 chunks) + wtrans (160 chunks)
  {
    const unsigned short* hs = (const unsigned short*)hist_src;
    unsigned short* hd = (unsigned short*)hist_dst;
    int* sd = lds;
    for (int w = bid; w < 196 + 160; w += 256) {
      if (w < 196) {
        int n = w * 256 + tid;
        int run = 0;
        if (n < N_NODES) {
          int so = 0;
#pragma unroll 8
          for (int c = 0; c < NCHUNK; ++c) so += hs[(long)c * NBT + n];
          norm_src[n] = rsqrtf((float)max(so, 1));
#pragma unroll 8
          for (int c = 0; c < NCHUNK; ++c) {
            int t = hd[(long)c * NBT + n];
            hd[(long)c * NBT + n] = (unsigned short)run;
            run += t;
          }
          deg_in[n] = run;
          norm_dst[n] = rsqrtf((float)max(run, 1));
        }
        __syncthreads();
        sd[tid] = run;
        __syncthreads();
        for (int s = 128; s > 0; s >>= 1) {
          if (tid < s) sd[tid] += sd[tid + s];
          __syncthreads();
        }
        if (tid == 0) partial[w] = sd[0];
        __syncthreads();
      } else {
        int i = (w - 196) * 256 + tid;
        if (i < 128 * 256) {
          int n = i >> 8, k = i & 255;
          W1T[i] = (f16)W1[k * 128 + n];
        } else {
          int j = i - 128 * 256;  // j < 64*128 since total chunks exact
          int n = j >> 7, k = j & 127;
          W2T[j] = (f16)W2[k * 64 + n];
        }
      }
    }
  }
  grid.sync();

  // ---------------- Phase C: scan partial[196] (block 0 only)
  if (bid == 0) {
    int* sd = lds;
    int v = (tid < 196) ? partial[tid] : 0;
    sd[tid] = v;
    __syncthreads();
    for (int off = 1; off < 256; off <<= 1) {
      int t = sd[tid] + ((tid >= off) ? sd[tid - off] : 0);
      __syncthreads();
      sd[tid] = t;
      __syncthreads();
    }
    if (tid < 196) partial[tid] = sd[tid] - v;  // exclusive
  }
  grid.sync();

  // ---------------- Phase D: rowptr = scan(deg_in)
  {
    int* sd = lds;
    for (int w = bid; w < 196; w += 256) {
      int i = w * 256 + tid;
      int v = (i < N_NODES) ? deg_in[i] : 0;
      __syncthreads();
      sd[tid] = v;
      __syncthreads();
      for (int off = 1; off < 256; off <<= 1) {
        int t = sd[tid] + ((tid >= off) ? sd[tid - off] : 0);
        __syncthreads();
        sd[tid] = t;
        __syncthreads();
      }
      if (i < N_NODES) rowptr[i] = partial[w] + sd[tid] - v;
      if (w == 0 && tid == 0) rowptr[N_NODES] = N_EDGES;
      __syncthreads();
    }
  }
  grid.sync();

  // ---------------- Phase E: CSR fill (LDS cursors, plain stores)
  {
    int* cur = lds;
    const unsigned short* pref = (const unsigned short*)hist_dst;
    const int r = bid % NRANGE;
    const int c = bid / NRANGE;
    const int lo = r * NB;
    for (int i = tid; i < NB; i += 256) {
      int n = lo + i;
      cur[i] = (n < N_NODES) ? rowptr[n] + pref[(long)c * NBT + n] : 0;
    }
    __syncthreads();
    const int4* s4 = (const int4*)(src + c * EPC);
    const int4* d4 = (const int4*)(dst + c * EPC);
    for (int i = tid; i < EPC / 4; i += 256) {
      int4 s = s4[i];
      int4 d = d4[i];
      unsigned b;
      b = (unsigned)(d.x - lo);
      if (b < NB) col[atomicAdd(&cur[b], 1)] = s.x;
      b = (unsigned)(d.y - lo);
      if (b < NB) col[atomicAdd(&cur[b], 1)] = s.y;
      b = (unsigned)(d.z - lo);
      if (b < NB) col[atomicAdd(&cur[b], 1)] = s.z;
      b = (unsigned)(d.w - lo);
      if (b < NB) col[atomicAdd(&cur[b], 1)] = s.w;
    }
  }
}

// ------------------------------------------------------------- MFMA GEMM
// 64x64 tiles, 4 waves x 16 rows; W-tile in LDS (row pad +8 f16);
// gemm1 grid 1564 (~4 waves/SIMD), gemm2 grid 782.
template <int K, int NC, int TN, bool FP32IN>
__global__ __launch_bounds__(256) void gemm_mfma(
    const void* __restrict__ Xv, const f16* __restrict__ WT,
    const float* __restrict__ ns, f16* __restrict__ Mout) {
  constexpr int KI = K / 32;
  constexpr int COLBLK = NC / (TN * 16);
  constexpr int KP = K + 8;  // padded LDS row stride (f16)
  __shared__ f16 Bs[TN * 16 * KP];

  const int cb = blockIdx.x % COLBLK;
  const int rb = blockIdx.x / COLBLK;
  const int col0 = cb * TN * 16;
  const int wave = threadIdx.x >> 6;
  const int lane = threadIdx.x & 63;
  const int m = lane & 15;
  const int q = lane >> 4;
  const int row0 = rb * 64 + wave * 16;

  for (int idx = threadIdx.x; idx < TN * 16 * (K / 8); idx += 256) {
    int n = idx / (K / 8);
    int kk = idx % (K / 8);
    *(f16x8*)(Bs + n * KP + kk * 8) =
        *(const f16x8*)(WT + (long)(col0 + n) * K + kk * 8);
  }
  __syncthreads();

  const int ra = min(row0 + m, N_NODES - 1);
  const float s = FP32IN ? ns[ra] : 0.f;

  f32x4 acc[TN];
#pragma unroll
  for (int t = 0; t < TN; ++t) acc[t] = (f32x4){0.f, 0.f, 0.f, 0.f};

#pragma unroll
  for (int ki = 0; ki < KI; ++ki) {
    const int kb = ki * 32 + q * 8;
    f16x8 a;
    if (FP32IN) {
      const float* X = (const float*)Xv;
      const float* p = X + (long)ra * K + kb;
      float4 u0 = *(const float4*)p;
      float4 u1 = *(const float4*)(p + 4);
      a[0] = (f16)(u0.x * s); a[1] = (f16)(u0.y * s);
      a[2] = (f16)(u0.z * s); a[3] = (f16)(u0.w * s);
      a[4] = (f16)(u1.x * s); a[5] = (f16)(u1.y * s);
      a[6] = (f16)(u1.z * s); a[7] = (f16)(u1.w * s);
    } else {
      const f16* X = (const f16*)Xv;
      a = *(const f16x8*)(X + (long)ra * K + kb);
    }
#pragma unroll
    for (int t = 0; t < TN; ++t) {
      f16x8 b = *(const f16x8*)(Bs + (t * 16 + m) * KP + kb);
      acc[t] = __builtin_amdgcn_mfma_f32_16x16x32_f16(a, b, acc[t], 0, 0, 0);
    }
  }

#pragma unroll
  for (int r = 0; r < 4; ++r) {
    int row = row0 + q * 4 + r;
    if (row < N_NODES) {
#pragma unroll
      for (int t = 0; t < TN; ++t)
        Mout[(long)row * NC + col0 + t * 16 + m] = (f16)acc[t][r];
    }
  }
}

// ------------------------------------------------------------- gather-agg
// R6/R10 measured-best form: wave = 1 dst node, full rows, EPW groups of
// LPR lanes, f16x8 (16 B/lane), group-stride + unroll 2.
__global__ __launch_bounds__(256) void gather1_kernel(
    const f16* __restrict__ M, const int* __restrict__ rowptr,
    const int* __restrict__ col, const float* __restrict__ nd,
    const float* __restrict__ ns, const float* __restrict__ b,
    f16* __restrict__ out) {
  constexpr int LPR = 16;       // 128 f16 = 256 B row / 16 B per lane
  constexpr int EPW = 64 / LPR; // 4 edges in parallel
  const int wave = threadIdx.x >> 6;
  const int lane = threadIdx.x & 63;
  const int eg = lane / LPR;
  const int t = lane % LPR;
  const int n = blockIdx.x * 4 + wave;
  if (n >= N_NODES) return;
  const int beg = rowptr[n];
  const int end = rowptr[n + 1];

  float acc[8];
#pragma unroll
  for (int j = 0; j < 8; ++j) acc[j] = 0.f;

  int i = beg + eg;
  for (; i + EPW < end; i += 2 * EPW) {
    int s0 = col[i];
    int s1 = col[i + EPW];
    f16x8 v0 = *(const f16x8*)(M + (long)s0 * HIDDEN + t * 8);
    f16x8 v1 = *(const f16x8*)(M + (long)s1 * HIDDEN + t * 8);
#pragma unroll
    for (int j = 0; j < 8; ++j) acc[j] += (float)v0[j] + (float)v1[j];
  }
  if (i < end) {
    int s0 = col[i];
    f16x8 v0 = *(const f16x8*)(M + (long)s0 * HIDDEN + t * 8);
#pragma unroll
    for (int j = 0; j < 8; ++j) acc[j] += (float)v0[j];
  }

#pragma unroll
  for (int m2 = LPR; m2 < 64; m2 <<= 1)
#pragma unroll
    for (int j = 0; j < 8; ++j) acc[j] += __shfl_xor(acc[j], m2, 64);

  if (eg == 0) {
    float s = nd[n];
    float sn = ns[n];
    float4 bb0 = *(const float4*)(b + t * 8);
    float4 bb1 = *(const float4*)(b + t * 8 + 4);
    f16x8 o;
    o[0] = (f16)(fmaxf(acc[0] * s + bb0.x, 0.f) * sn);
    o[1] = (f16)(fmaxf(acc[1] * s + bb0.y, 0.f) * sn);
    o[2] = (f16)(fmaxf(acc[2] * s + bb0.z, 0.f) * sn);
    o[3] = (f16)(fmaxf(acc[3] * s + bb0.w, 0.f) * sn);
    o[4] = (f16)(fmaxf(acc[4] * s + bb1.x, 0.f) * sn);
    o[5] = (f16)(fmaxf(acc[5] * s + bb1.y, 0.f) * sn);
    o[6] = (f16)(fmaxf(acc[6] * s + bb1.z, 0.f) * sn);
    o[7] = (f16)(fmaxf(acc[7] * s + bb1.w, 0.f) * sn);
    *(f16x8*)(out + (long)n * HIDDEN + t * 8) = o;
  }
}

__global__ __launch_bounds__(256) void gather2_kernel(
    const f16* __restrict__ M, const int* __restrict__ rowptr,
    const int* __restrict__ col, const float* __restrict__ nd,
    const float* __restrict__ b, float* __restrict__ out) {
  constexpr int LPR = 8;        // 64 f16 = 128 B row / 16 B per lane
  constexpr int EPW = 64 / LPR; // 8 edges in parallel
  const int wave = threadIdx.x >> 6;
  const int lane = threadIdx.x & 63;
  const int eg = lane / LPR;
  const int t = lane % LPR;
  const int n = blockIdx.x * 4 + wave;
  if (n >= N_NODES) return;
  const int beg = rowptr[n];
  const int end = rowptr[n + 1];

  float acc[8];
#pragma unroll
  for (int j = 0; j < 8; ++j) acc[j] = 0.f;

  int i = beg + eg;
  for (; i + EPW < end; i += 2 * EPW) {
    int s0 = col[i];
    int s1 = col[i + EPW];
    f16x8 v0 = *(const f16x8*)(M + (long)s0 * OUT_FEATS + t * 8);
    f16x8 v1 = *(const f16x8*)(M + (long)s1 * OUT_FEATS + t * 8);
#pragma unroll
    for (int j = 0; j < 8; ++j) acc[j] += (float)v0[j] + (float)v1[j];
  }
  if (i < end) {
    int s0 = col[i];
    f16x8 v0 = *(const f16x8*)(M + (long)s0 * OUT_FEATS + t * 8);
#pragma unroll
    for (int j = 0; j < 8; ++j) acc[j] += (float)v0[j];
  }

#pragma unroll
  for (int m2 = LPR; m2 < 64; m2 <<= 1)
#pragma unroll
    for (int j = 0; j < 8; ++j) acc[j] += __shfl_xor(acc[j], m2, 64);

  if (eg == 0) {
    float s = nd[n];
    float4 bb0 = *(const float4*)(b + t * 8);
    float4 bb1 = *(const float4*)(b + t * 8 + 4);
    float4 o0, o1;
    o0.x = acc[0] * s + bb0.x;
    o0.y = acc[1] * s + bb0.y;
    o0.z = acc[2] * s + bb0.z;
    o0.w = acc[3] * s + bb0.w;
    o1.x = acc[4] * s + bb1.x;
    o1.y = acc[5] * s + bb1.y;
    o1.z = acc[6] * s + bb1.z;
    o1.w = acc[7] * s + bb1.w;
    *(float4*)(out + (long)n * OUT_FEATS + t * 8) = o0;
    *(float4*)(out + (long)n * OUT_FEATS + t * 8 + 4) = o1;
  }
}

extern "C" void kernel_launch(void* const* d_in, const int* in_sizes, int n_in,
                              void* d_out, int out_size, void* d_ws,
                              size_t ws_size, hipStream_t stream) {
  const float* x = (const float*)d_in[0];
  const int* src = (const int*)d_in[1];
  const int* dst = (const int*)d_in[2];
  const float* W1 = (const float*)d_in[3];
  const float* b1 = (const float*)d_in[4];
  const float* W2 = (const float*)d_in[5];
  const float* b2 = (const float*)d_in[6];
  float* out = (float*)d_out;

  // ---- workspace layout
  int* wi = (int*)d_ws;
  int* partial = wi;            // [256]
  int* rowptr = wi + 256;       // [50001] (pad to 50004)
  int* deg_in = wi + 50260;     // [50000]
  int* col = wi + 100260;       // [800000] -> ends at int 900260
  float* wf = (float*)d_ws + 900260;
  float* norm_src = wf;         // [50000]
  float* norm_dst = wf + 50000; // [50000]
  f16* fh = (f16*)(wf + 100000);
  f16* W1T = fh;                // [128*256]
  f16* W2T = fh + 128 * 256;    // [64*128]
  f16* m1 = fh + 128 * 256 + 64 * 128;  // [50048*128]
  f16* h1p = m1 + (long)50048 * 128;    // [50048*128]
  f16* m2 = h1p + (long)50048 * 128;    // [50048*64]

  // hist overlay on m1/h1p/m2 region: 16.8 MB < 32 MB region; dead before
  // gemm1 writes m1 (stream-ordered).
  unsigned* hist_src = (unsigned*)m1;                       // u16[NCHUNK*NBT]
  unsigned* hist_dst = hist_src + (long)NCHUNK * NBT / 2;   // u16[NCHUNK*NBT]

  const int rowblk = (N_NODES + 63) / 64;  // 782

  // ---- fused preprocessing (1 cooperative dispatch, 256 blocks)
  void* args[] = {(void*)&src,      (void*)&dst,      (void*)&W1,
                  (void*)&W2,       (void*)&hist_src, (void*)&hist_dst,
                  (void*)&deg_in,   (void*)&norm_src, (void*)&norm_dst,
                  (void*)&partial,  (void*)&rowptr,   (void*)&col,
                  (void*)&W1T,      (void*)&W2T};
  hipLaunchCooperativeKernel((void*)prep_kernel, dim3(NRANGE * NCHUNK),
                             dim3(256), args, 0, stream);

  // ---- layer 1
  gemm_mfma<IN_FEATS, HIDDEN, 4, true>
      <<<rowblk * 2, 256, 0, stream>>>(x, W1T, norm_src, m1);
  gather1_kernel<<<(N_NODES + 3) / 4, 256, 0, stream>>>(m1, rowptr, col,
                                                        norm_dst, norm_src, b1,
                                                        h1p);

  // ---- layer 2
  gemm_mfma<HIDDEN, OUT_FEATS, 4, false>
      <<<rowblk, 256, 0, stream>>>(h1p, W2T, norm_src, m2);
  gather2_kernel<<<(N_NODES + 3) / 4, 256, 0, stream>>>(m2, rowptr, col,
                                                        norm_dst, b2, out);
}

// Round 12
// 239.162 us; speedup vs baseline: 1.5493x; 1.5493x over previous
//
#include <hip/hip_runtime.h>

#define N_NODES 50000
#define N_EDGES 800000
#define IN_FEATS 256
#define HIDDEN 128
#define OUT_FEATS 64

// ---- LDS-histogram decomposition (packed u16 counters) ----
#define NB 16384             // bins per range (2 bins/u32 word -> 32 KB LDS)
#define NRANGE 4             // ceil(50000/16384)
#define NBT (NRANGE * NB)    // 65536 padded bins per copy (u16 each)
#define NCHUNK 64            // edge chunks (= privatized copies)
#define EPC 12500            // edges per chunk; per-bin count <= 12500 < 2^16

typedef _Float16 f16;
typedef _Float16 f16x8 __attribute__((ext_vector_type(8)));
typedef float f32x4 __attribute__((ext_vector_type(4)));

// ---------------------------------------------------------- LDS histogram
// Zero global atomics (gfx950 global atomics cost ~32B beyond-L2 traffic
// each regardless of locality — R3/R4). Blocks 0-159 also do one 256-elem
// W-transpose chunk (folds the old wtrans dispatch; independent work).
// NO cooperative sync anywhere — R11: grid.sync costs ~30 us on gfx950.
__global__ __launch_bounds__(256) void hist_kernel(
    const int* __restrict__ src, const int* __restrict__ dst,
    unsigned* __restrict__ hist_src, unsigned* __restrict__ hist_dst,
    const float* __restrict__ W1, const float* __restrict__ W2,
    f16* __restrict__ W1T, f16* __restrict__ W2T) {
  __shared__ unsigned ls[NB / 2];   // 32 KB
  __shared__ unsigned ld2[NB / 2];  // 32 KB
  const int r = blockIdx.x % NRANGE;
  const int c = blockIdx.x / NRANGE;
  const int lo = r * NB;
  for (int i = threadIdx.x; i < NB / 2; i += 256) {
    ls[i] = 0;
    ld2[i] = 0;
  }
  __syncthreads();
  const int4* s4 = (const int4*)(src + c * EPC);
  const int4* d4 = (const int4*)(dst + c * EPC);
  for (int i = threadIdx.x; i < EPC / 4; i += 256) {
    int4 s = s4[i];
    int4 d = d4[i];
    unsigned b;
    b = (unsigned)(s.x - lo); if (b < NB) atomicAdd(&ls[b >> 1], 1u << ((b & 1) << 4));
    b = (unsigned)(s.y - lo); if (b < NB) atomicAdd(&ls[b >> 1], 1u << ((b & 1) << 4));
    b = (unsigned)(s.z - lo); if (b < NB) atomicAdd(&ls[b >> 1], 1u << ((b & 1) << 4));
    b = (unsigned)(s.w - lo); if (b < NB) atomicAdd(&ls[b >> 1], 1u << ((b & 1) << 4));
    b = (unsigned)(d.x - lo); if (b < NB) atomicAdd(&ld2[b >> 1], 1u << ((b & 1) << 4));
    b = (unsigned)(d.y - lo); if (b < NB) atomicAdd(&ld2[b >> 1], 1u << ((b & 1) << 4));
    b = (unsigned)(d.z - lo); if (b < NB) atomicAdd(&ld2[b >> 1], 1u << ((b & 1) << 4));
    b = (unsigned)(d.w - lo); if (b < NB) atomicAdd(&ld2[b >> 1], 1u << ((b & 1) << 4));
  }
  __syncthreads();
  unsigned* hs = hist_src + ((long)c * NBT + lo) / 2;
  unsigned* hd = hist_dst + ((long)c * NBT + lo) / 2;
  for (int i = threadIdx.x; i < NB / 2; i += 256) {
    hs[i] = ls[i];
    hd[i] = ld2[i];
  }
  // folded wtrans: 160 chunks of 256 elems (32768 W1T + 8192 W2T)
  if (blockIdx.x < 160) {
    int i = blockIdx.x * 256 + threadIdx.x;
    if (i < 128 * 256) {
      int n = i >> 8, k = i & 255;
      W1T[i] = (f16)W1[k * 128 + n];
    } else {
      int j = i - 128 * 256;
      int n = j >> 7, k = j & 127;
      W2T[j] = (f16)W2[k * 64 + n];
    }
  }
}

// sum copies -> norms; hist_dst -> exclusive prefix over copies (u16; max
// in-degree ~50 << 2^16); emits per-block degree sums (folded scan1).
__global__ __launch_bounds__(256) void reduce_kernel(
    const unsigned* __restrict__ hist_src, unsigned* __restrict__ hist_dst,
    int* __restrict__ deg_in, float* __restrict__ norm_src,
    float* __restrict__ norm_dst, int* __restrict__ partial) {
  const unsigned short* hs = (const unsigned short*)hist_src;
  unsigned short* hd = (unsigned short*)hist_dst;
  int n = blockIdx.x * 256 + threadIdx.x;
  int run = 0;
  if (n < N_NODES) {
    int so = 0;
#pragma unroll 8
    for (int c = 0; c < NCHUNK; ++c) so += hs[(long)c * NBT + n];
    norm_src[n] = rsqrtf((float)max(so, 1));
#pragma unroll 8
    for (int c = 0; c < NCHUNK; ++c) {
      int t = hd[(long)c * NBT + n];
      hd[(long)c * NBT + n] = (unsigned short)run;
      run += t;
    }
    deg_in[n] = run;
    norm_dst[n] = rsqrtf((float)max(run, 1));
  }
  __shared__ int sd[256];
  sd[threadIdx.x] = run;
  __syncthreads();
  for (int s = 128; s > 0; s >>= 1) {
    if (threadIdx.x < s) sd[threadIdx.x] += sd[threadIdx.x + s];
    __syncthreads();
  }
  if (threadIdx.x == 0) partial[blockIdx.x] = sd[0];
}

// ------------------------------------------------- scan (scan2 folded in)
// Each block redundantly block-scans the 196 partials in LDS (~1 us) to get
// its own base — removes the single-block scan2 dispatch.
__global__ __launch_bounds__(256) void scan3(const int* __restrict__ deg,
                                             const int* __restrict__ partial,
                                             int* __restrict__ rowptr) {
  __shared__ int sd[256];
  __shared__ int sp[256];
  const int w = blockIdx.x;
  // scan partials (inclusive) in sp
  int pv = (threadIdx.x < 196) ? partial[threadIdx.x] : 0;
  sp[threadIdx.x] = pv;
  __syncthreads();
  for (int off = 1; off < 256; off <<= 1) {
    int t = sp[threadIdx.x] +
            ((threadIdx.x >= off) ? sp[threadIdx.x - off] : 0);
    __syncthreads();
    sp[threadIdx.x] = t;
    __syncthreads();
  }
  const int base = (w == 0) ? 0 : sp[w - 1];
  // scan this block's node chunk
  int i = w * 256 + threadIdx.x;
  int v = (i < N_NODES) ? deg[i] : 0;
  sd[threadIdx.x] = v;
  __syncthreads();
  for (int off = 1; off < 256; off <<= 1) {
    int t = sd[threadIdx.x] +
            ((threadIdx.x >= off) ? sd[threadIdx.x - off] : 0);
    __syncthreads();
    sd[threadIdx.x] = t;
    __syncthreads();
  }
  if (i < N_NODES) rowptr[i] = base + sd[threadIdx.x] - v;
  if (w == 0 && threadIdx.x == 0) rowptr[N_NODES] = N_EDGES;
}

// ------------------------------------------------------------- CSR fill
__global__ __launch_bounds__(256) void fill_csr(
    const int* __restrict__ src, const int* __restrict__ dst,
    const int* __restrict__ rowptr, const unsigned* __restrict__ pref32,
    int* __restrict__ col) {
  __shared__ int cur[NB];  // 64 KB
  const unsigned short* pref = (const unsigned short*)pref32;
  const int r = blockIdx.x % NRANGE;
  const int c = blockIdx.x / NRANGE;
  const int lo = r * NB;
  for (int i = threadIdx.x; i < NB; i += 256) {
    int n = lo + i;
    cur[i] = (n < N_NODES) ? rowptr[n] + pref[(long)c * NBT + n] : 0;
  }
  __syncthreads();
  const int4* s4 = (const int4*)(src + c * EPC);
  const int4* d4 = (const int4*)(dst + c * EPC);
  for (int i = threadIdx.x; i < EPC / 4; i += 256) {
    int4 s = s4[i];
    int4 d = d4[i];
    unsigned b;
    b = (unsigned)(d.x - lo);
    if (b < NB) col[atomicAdd(&cur[b], 1)] = s.x;
    b = (unsigned)(d.y - lo);
    if (b < NB) col[atomicAdd(&cur[b], 1)] = s.y;
    b = (unsigned)(d.z - lo);
    if (b < NB) col[atomicAdd(&cur[b], 1)] = s.z;
    b = (unsigned)(d.w - lo);
    if (b < NB) col[atomicAdd(&cur[b], 1)] = s.w;
  }
}

// ------------------------------------------------------------- MFMA GEMM
// 64x64 tiles, 4 waves x 16 rows; W-tile in LDS (row pad +8 f16);
// gemm1 grid 1564 (~4 waves/SIMD), gemm2 grid 782.
template <int K, int NC, int TN, bool FP32IN>
__global__ __launch_bounds__(256) void gemm_mfma(
    const void* __restrict__ Xv, const f16* __restrict__ WT,
    const float* __restrict__ ns, f16* __restrict__ Mout) {
  constexpr int KI = K / 32;
  constexpr int COLBLK = NC / (TN * 16);
  constexpr int KP = K + 8;  // padded LDS row stride (f16)
  __shared__ f16 Bs[TN * 16 * KP];

  const int cb = blockIdx.x % COLBLK;
  const int rb = blockIdx.x / COLBLK;
  const int col0 = cb * TN * 16;
  const int wave = threadIdx.x >> 6;
  const int lane = threadIdx.x & 63;
  const int m = lane & 15;
  const int q = lane >> 4;
  const int row0 = rb * 64 + wave * 16;

  for (int idx = threadIdx.x; idx < TN * 16 * (K / 8); idx += 256) {
    int n = idx / (K / 8);
    int kk = idx % (K / 8);
    *(f16x8*)(Bs + n * KP + kk * 8) =
        *(const f16x8*)(WT + (long)(col0 + n) * K + kk * 8);
  }
  __syncthreads();

  const int ra = min(row0 + m, N_NODES - 1);
  const float s = FP32IN ? ns[ra] : 0.f;

  f32x4 acc[TN];
#pragma unroll
  for (int t = 0; t < TN; ++t) acc[t] = (f32x4){0.f, 0.f, 0.f, 0.f};

#pragma unroll
  for (int ki = 0; ki < KI; ++ki) {
    const int kb = ki * 32 + q * 8;
    f16x8 a;
    if (FP32IN) {
      const float* X = (const float*)Xv;
      const float* p = X + (long)ra * K + kb;
      float4 u0 = *(const float4*)p;
      float4 u1 = *(const float4*)(p + 4);
      a[0] = (f16)(u0.x * s); a[1] = (f16)(u0.y * s);
      a[2] = (f16)(u0.z * s); a[3] = (f16)(u0.w * s);
      a[4] = (f16)(u1.x * s); a[5] = (f16)(u1.y * s);
      a[6] = (f16)(u1.z * s); a[7] = (f16)(u1.w * s);
    } else {
      const f16* X = (const f16*)Xv;
      a = *(const f16x8*)(X + (long)ra * K + kb);
    }
#pragma unroll
    for (int t = 0; t < TN; ++t) {
      f16x8 b = *(const f16x8*)(Bs + (t * 16 + m) * KP + kb);
      acc[t] = __builtin_amdgcn_mfma_f32_16x16x32_f16(a, b, acc[t], 0, 0, 0);
    }
  }

#pragma unroll
  for (int r = 0; r < 4; ++r) {
    int row = row0 + q * 4 + r;
    if (row < N_NODES) {
#pragma unroll
      for (int t = 0; t < TN; ++t)
        Mout[(long)row * NC + col0 + t * 16 + m] = (f16)acc[t][r];
    }
  }
}

// ------------------------------------------------------------- gather-agg
// R6/R10 measured-best form: wave = 1 dst node, full rows, EPW groups of
// LPR lanes, f16x8 (16 B/lane), group-stride + unroll 2. Gather is at its
// L2/L3 random-row service floor (FETCH ~109 MB = 8-XCD compulsory).
__global__ __launch_bounds__(256) void gather1_kernel(
    const f16* __restrict__ M, const int* __restrict__ rowptr,
    const int* __restrict__ col, const float* __restrict__ nd,
    const float* __restrict__ ns, const float* __restrict__ b,
    f16* __restrict__ out) {
  constexpr int LPR = 16;       // 128 f16 = 256 B row / 16 B per lane
  constexpr int EPW = 64 / LPR; // 4 edges in parallel
  const int wave = threadIdx.x >> 6;
  const int lane = threadIdx.x & 63;
  const int eg = lane / LPR;
  const int t = lane % LPR;
  const int n = blockIdx.x * 4 + wave;
  if (n >= N_NODES) return;
  const int beg = rowptr[n];
  const int end = rowptr[n + 1];

  float acc[8];
#pragma unroll
  for (int j = 0; j < 8; ++j) acc[j] = 0.f;

  int i = beg + eg;
  for (; i + EPW < end; i += 2 * EPW) {
    int s0 = col[i];
    int s1 = col[i + EPW];
    f16x8 v0 = *(const f16x8*)(M + (long)s0 * HIDDEN + t * 8);
    f16x8 v1 = *(const f16x8*)(M + (long)s1 * HIDDEN + t * 8);
#pragma unroll
    for (int j = 0; j < 8; ++j) acc[j] += (float)v0[j] + (float)v1[j];
  }
  if (i < end) {
    int s0 = col[i];
    f16x8 v0 = *(const f16x8*)(M + (long)s0 * HIDDEN + t * 8);
#pragma unroll
    for (int j = 0; j < 8; ++j) acc[j] += (float)v0[j];
  }

#pragma unroll
  for (int m2 = LPR; m2 < 64; m2 <<= 1)
#pragma unroll
    for (int j = 0; j < 8; ++j) acc[j] += __shfl_xor(acc[j], m2, 64);

  if (eg == 0) {
    float s = nd[n];
    float sn = ns[n];
    float4 bb0 = *(const float4*)(b + t * 8);
    float4 bb1 = *(const float4*)(b + t * 8 + 4);
    f16x8 o;
    o[0] = (f16)(fmaxf(acc[0] * s + bb0.x, 0.f) * sn);
    o[1] = (f16)(fmaxf(acc[1] * s + bb0.y, 0.f) * sn);
    o[2] = (f16)(fmaxf(acc[2] * s + bb0.z, 0.f) * sn);
    o[3] = (f16)(fmaxf(acc[3] * s + bb0.w, 0.f) * sn);
    o[4] = (f16)(fmaxf(acc[4] * s + bb1.x, 0.f) * sn);
    o[5] = (f16)(fmaxf(acc[5] * s + bb1.y, 0.f) * sn);
    o[6] = (f16)(fmaxf(acc[6] * s + bb1.z, 0.f) * sn);
    o[7] = (f16)(fmaxf(acc[7] * s + bb1.w, 0.f) * sn);
    *(f16x8*)(out + (long)n * HIDDEN + t * 8) = o;
  }
}

__global__ __launch_bounds__(256) void gather2_kernel(
    const f16* __restrict__ M, const int* __restrict__ rowptr,
    const int* __restrict__ col, const float* __restrict__ nd,
    const float* __restrict__ b, float* __restrict__ out) {
  constexpr int LPR = 8;        // 64 f16 = 128 B row / 16 B per lane
  constexpr int EPW = 64 / LPR; // 8 edges in parallel
  const int wave = threadIdx.x >> 6;
  const int lane = threadIdx.x & 63;
  const int eg = lane / LPR;
  const int t = lane % LPR;
  const int n = blockIdx.x * 4 + wave;
  if (n >= N_NODES) return;
  const int beg = rowptr[n];
  const int end = rowptr[n + 1];

  float acc[8];
#pragma unroll
  for (int j = 0; j < 8; ++j) acc[j] = 0.f;

  int i = beg + eg;
  for (; i + EPW < end; i += 2 * EPW) {
    int s0 = col[i];
    int s1 = col[i + EPW];
    f16x8 v0 = *(const f16x8*)(M + (long)s0 * OUT_FEATS + t * 8);
    f16x8 v1 = *(const f16x8*)(M + (long)s1 * OUT_FEATS + t * 8);
#pragma unroll
    for (int j = 0; j < 8; ++j) acc[j] += (float)v0[j] + (float)v1[j];
  }
  if (i < end) {
    int s0 = col[i];
    f16x8 v0 = *(const f16x8*)(M + (long)s0 * OUT_FEATS + t * 8);
#pragma unroll
    for (int j = 0; j < 8; ++j) acc[j] += (float)v0[j];
  }

#pragma unroll
  for (int m2 = LPR; m2 < 64; m2 <<= 1)
#pragma unroll
    for (int j = 0; j < 8; ++j) acc[j] += __shfl_xor(acc[j], m2, 64);

  if (eg == 0) {
    float s = nd[n];
    float4 bb0 = *(const float4*)(b + t * 8);
    float4 bb1 = *(const float4*)(b + t * 8 + 4);
    float4 o0, o1;
    o0.x = acc[0] * s + bb0.x;
    o0.y = acc[1] * s + bb0.y;
    o0.z = acc[2] * s + bb0.z;
    o0.w = acc[3] * s + bb0.w;
    o1.x = acc[4] * s + bb1.x;
    o1.y = acc[5] * s + bb1.y;
    o1.z = acc[6] * s + bb1.z;
    o1.w = acc[7] * s + bb1.w;
    *(float4*)(out + (long)n * OUT_FEATS + t * 8) = o0;
    *(float4*)(out + (long)n * OUT_FEATS + t * 8 + 4) = o1;
  }
}

extern "C" void kernel_launch(void* const* d_in, const int* in_sizes, int n_in,
                              void* d_out, int out_size, void* d_ws,
                              size_t ws_size, hipStream_t stream) {
  const float* x = (const float*)d_in[0];
  const int* src = (const int*)d_in[1];
  const int* dst = (const int*)d_in[2];
  const float* W1 = (const float*)d_in[3];
  const float* b1 = (const float*)d_in[4];
  const float* W2 = (const float*)d_in[5];
  const float* b2 = (const float*)d_in[6];
  float* out = (float*)d_out;

  // ---- workspace layout
  int* wi = (int*)d_ws;
  int* partial = wi;            // [256]
  int* rowptr = wi + 256;       // [50001] (pad to 50004)
  int* deg_in = wi + 50260;     // [50000]
  int* col = wi + 100260;       // [800000] -> ends at int 900260
  float* wf = (float*)d_ws + 900260;
  float* norm_src = wf;         // [50000]
  float* norm_dst = wf + 50000; // [50000]
  f16* fh = (f16*)(wf + 100000);
  f16* W1T = fh;                // [128*256]
  f16* W2T = fh + 128 * 256;    // [64*128]
  f16* m1 = fh + 128 * 256 + 64 * 128;  // [50048*128]
  f16* h1p = m1 + (long)50048 * 128;    // [50048*128]
  f16* m2 = h1p + (long)50048 * 128;    // [50048*64]

  // hist overlay on m1/h1p/m2 region: 16.8 MB < 32 MB region; dead before
  // gemm1 writes m1 (stream-ordered).
  unsigned* hist_src = (unsigned*)m1;                       // u16[NCHUNK*NBT]
  unsigned* hist_dst = hist_src + (long)NCHUNK * NBT / 2;   // u16[NCHUNK*NBT]

  const int nb_nodes = (N_NODES + 255) / 256;  // 196
  const int rowblk = (N_NODES + 63) / 64;      // 782

  // ---- degrees + norms + CSR (no global atomics, no grid sync)
  hist_kernel<<<NRANGE * NCHUNK, 256, 0, stream>>>(src, dst, hist_src,
                                                   hist_dst, W1, W2, W1T, W2T);
  reduce_kernel<<<nb_nodes, 256, 0, stream>>>(hist_src, hist_dst, deg_in,
                                              norm_src, norm_dst, partial);
  scan3<<<nb_nodes, 256, 0, stream>>>(deg_in, partial, rowptr);
  fill_csr<<<NRANGE * NCHUNK, 256, 0, stream>>>(src, dst, rowptr, hist_dst,
                                                col);

  // ---- layer 1
  gemm_mfma<IN_FEATS, HIDDEN, 4, true>
      <<<rowblk * 2, 256, 0, stream>>>(x, W1T, norm_src, m1);
  gather1_kernel<<<(N_NODES + 3) / 4, 256, 0, stream>>>(m1, rowptr, col,
                                                        norm_dst, norm_src, b1,
                                                        h1p);

  // ---- layer 2
  gemm_mfma<HIDDEN, OUT_FEATS, 4, false>
      <<<rowblk, 256, 0, stream>>>(h1p, W2T, norm_src, m2);
  gather2_kernel<<<(N_NODES + 3) / 4, 256, 0, stream>>>(m2, rowptr, col,
                                                        norm_dst, b2, out);
}